// Round 13
// baseline (6126.889 us; speedup 1.0000x reference)
//
#include <hip/hip_runtime.h>
#include <math.h>

#define S_LEN 200
#define BATCH 64
#define HID   512
#define NTAG  22
#define TCH   40              // time-chunk for gates_x staging (MC=2560 = 20 x 128)
#define MC    (TCH*BATCH)     // 2560 rows per chunk GEMM
#define HSTR  (HID*BATCH + 256)   // padded h-slice stride
#define ASTR  64              // ints per arrival stripe (256 B -> own cacheline)

typedef unsigned short u16;
typedef unsigned int   u32;

__device__ __forceinline__ float bf2f(u16 u){
  union { u32 ui; float f; } v; v.ui = ((u32)u) << 16; return v.f;
}

__device__ __forceinline__ float rdlane(float x, int lane){
  return __int_as_float(__builtin_amdgcn_readlane(__float_as_int(x), lane));
}

// ---------------------------------------------------------------------------
__global__ void k_detect(const u32* __restrict__ w, int* __restrict__ flag){
  __shared__ int cnt;
  if (threadIdx.x == 0) cnt = 0;
  __syncthreads();
  int hits = 0;
  for (int i = threadIdx.x; i < 16384; i += 256){
    u32 e = (w[i] & 0x7F80u);
    if (e >= 0x3800u && e <= 0x4080u) hits++;
  }
  atomicAdd(&cnt, hits);
  __syncthreads();
  if (threadIdx.x == 0) *flag = (cnt > 8192) ? 1 : 0;
}

__global__ void k_cvt_f(const void* __restrict__ src, float* __restrict__ dst,
                        int n, const int* __restrict__ flag){
  int i = blockIdx.x*blockDim.x + threadIdx.x;
  if (i >= n) return;
  if (*flag) dst[i] = bf2f(((const u16*)src)[i]);
  else       dst[i] = ((const float*)src)[i];
}

// W_out [1024][22] -> wpad [2][512][24]  (tag-padded, k-major per half)
__global__ void k_cvt_wt(const void* __restrict__ src, float* __restrict__ dst,
                         const int* __restrict__ flag){
  int i = blockIdx.x*blockDim.x + threadIdx.x;   // over 1024*24
  if (i >= 1024*24) return;
  int k = i / 24, tag = i % 24;
  float v = 0.f;
  if (tag < NTAG){
    v = (*flag) ? bf2f(((const u16*)src)[k*NTAG + tag])
                : ((const float*)src)[k*NTAG + tag];
  }
  int half = k >> 9, kk = k & 511;
  dst[((size_t)half*512 + kk)*24 + tag] = v;
}

__global__ void k_zero(float* __restrict__ p, int n){
  int i = blockIdx.x*blockDim.x + threadIdx.x;
  if (i < n) p[i] = 0.f;
}

// ---------------------------------------------------------------------------
// Build fwd_in/bwd_in [S][B][256] fp32.
__global__ __launch_bounds__(128)
void k_build(const int* __restrict__ ci, const int* __restrict__ lengths,
             const int* __restrict__ gid, const int* __restrict__ gm,
             const int* __restrict__ rgid, const int* __restrict__ rgm,
             const void* __restrict__ ctab, const void* __restrict__ gtab,
             const int* __restrict__ flag,
             float* __restrict__ fin, float* __restrict__ bin)
{
  int bs = blockIdx.x;              // b*S_LEN + s
  int b = bs / S_LEN, s = bs % S_LEN;
  int d = threadIdx.x;              // 0..127
  int isbf = *flag;
  int len = lengths[b];
  int sb = (s < len) ? (len - 1 - s) : s;
  size_t orow = ((size_t)s*BATCH + b)*256;

  {
    int cid = ci[bs];
    float cv = isbf ? bf2f(((const u16*)ctab)[(size_t)cid*128 + d])
                    : ((const float*)ctab)[(size_t)cid*128 + d];
    fin[orow + d] = cv;
    const int* gg = gid + (size_t)bs*8;
    const int* mm = gm  + (size_t)bs*8;
    float sum = 0.f, cntf = 0.f;
    for (int g = 0; g < 8; ++g){
      float m = (float)mm[g];
      int gw = gg[g];
      float gv = isbf ? bf2f(((const u16*)gtab)[(size_t)gw*128 + d])
                      : ((const float*)gtab)[(size_t)gw*128 + d];
      sum += m * gv; cntf += m;
    }
    fin[orow + 128 + d] = sum / fmaxf(cntf, 1.f);
  }
  {
    int bsr = b*S_LEN + sb;
    int cid = ci[bsr];
    float cv = isbf ? bf2f(((const u16*)ctab)[(size_t)cid*128 + d])
                    : ((const float*)ctab)[(size_t)cid*128 + d];
    bin[orow + d] = cv;
    const int* gg = rgid + (size_t)bsr*8;
    const int* mm = rgm  + (size_t)bsr*8;
    float sum = 0.f, cntf = 0.f;
    for (int g = 0; g < 8; ++g){
      float m = (float)mm[g];
      int gw = gg[g];
      float gv = isbf ? bf2f(((const u16*)gtab)[(size_t)gw*128 + d])
                      : ((const float*)gtab)[(size_t)gw*128 + d];
      sum += m * gv; cntf += m;
    }
    bin[orow + 128 + d] = sum / fmaxf(cntf, 1.f);
  }
}

// ---------------------------------------------------------------------------
// Chunked gates_x GEMM: C[dir][n][m] = A.W^T + bias (transposed store).
// 128x128 block tile, 256 threads, 8x8 microtile.
__global__ __launch_bounds__(256)
void k_gemm_ih(const float* __restrict__ Af, const float* __restrict__ Ab,
               const float* __restrict__ wih,   // [2][2048][256]
               const float* __restrict__ bias,  // [2][2048]
               float* __restrict__ gxc,         // [2][2048][MC]
               int t0)
{
  const int dir = blockIdx.z;
  const float* A = (dir ? Ab : Af) + (size_t)t0*BATCH*256;   // [MC][256]
  const float* W = wih + (size_t)dir*2048*256;
  const float* bi = bias + (size_t)dir*2048;
  float* C = gxc + (size_t)dir*2048*MC;
  const int m0 = blockIdx.y * 128;
  const int n0 = blockIdx.x * 128;
  const int tid = threadIdx.x;

  __shared__ float As[32][132];   // k-major, padded
  __shared__ float Ws[32][132];

  const int lrow = tid >> 3;        // 0..31
  const int lk   = (tid & 7) * 4;   // 0,4,..,28

  const int tx = tid & 15;          // n-frag
  const int ty = tid >> 4;          // m-frag

  float acc[8][8] = {};

  for (int k0 = 0; k0 < 256; k0 += 32){
    #pragma unroll
    for (int q = 0; q < 4; ++q){
      const int row = lrow + q*32;
      float4 a = *(const float4*)(A + (size_t)(m0+row)*256 + k0 + lk);
      float4 w = *(const float4*)(W + (size_t)(n0+row)*256 + k0 + lk);
      As[lk+0][row]=a.x; As[lk+1][row]=a.y; As[lk+2][row]=a.z; As[lk+3][row]=a.w;
      Ws[lk+0][row]=w.x; Ws[lk+1][row]=w.y; Ws[lk+2][row]=w.z; Ws[lk+3][row]=w.w;
    }
    __syncthreads();
    #pragma unroll 8
    for (int kk = 0; kk < 32; ++kk){
      float4 a0 = *(const float4*)(&As[kk][ty*8]);
      float4 a1 = *(const float4*)(&As[kk][ty*8+4]);
      float4 w0 = *(const float4*)(&Ws[kk][tx*8]);
      float4 w1 = *(const float4*)(&Ws[kk][tx*8+4]);
      float am[8] = {a0.x,a0.y,a0.z,a0.w,a1.x,a1.y,a1.z,a1.w};
      float wn[8] = {w0.x,w0.y,w0.z,w0.w,w1.x,w1.y,w1.z,w1.w};
      #pragma unroll
      for (int i = 0; i < 8; ++i)
        #pragma unroll
        for (int jj = 0; jj < 8; ++jj)
          acc[i][jj] += am[i]*wn[jj];
    }
    __syncthreads();
  }

  #pragma unroll
  for (int jj = 0; jj < 8; ++jj){
    const int n = n0 + tx*8 + jj;
    const float bj = bi[n];
    #pragma unroll
    for (int i = 0; i < 8; i += 4){
      float4 o = make_float4(acc[i][jj]+bj, acc[i+1][jj]+bj,
                             acc[i+2][jj]+bj, acc[i+3][jj]+bj);
      *(float4*)(C + (size_t)n*MC + m0 + ty*8 + i) = o;
    }
  }
}

// ---------------------------------------------------------------------------
// Persistent LSTM with flag sync. r9/r10 (both FAILED, same absmax) had
// relaxed h-store + relaxed counter-add: no guarantee h is at L3 when the
// counter ticks. r8's global 128-block fan-in masked the window with slack;
// the per-wave 16-block gate catches it. Fix = release/acquire message
// passing:
//   producer: fetch_add(RELEASE, AGENT)  -> prior stores (all threads of the
//             block, ordered via __syncthreads happens-before; mechanically
//             the release's L2-writeback covers them) reach the coherent
//             point before the signal is visible
//   consumer: relaxed spin, then ONE ACQUIRE load (cache-inv), h address
//             data-dependent on its result.
// Per-wave release kept (wave uw waits only for its 16 producer blocks).
// Math / accumulation order byte-identical to r8.
__global__ __launch_bounds__(512, 1)
void k_lstm(const float* __restrict__ whh,    // [2][2048][512]
            const float* __restrict__ gxc,    // [2][2048][MC]
            float* __restrict__ cbuf,         // [2][512][64]
            float* __restrict__ hseq,         // [2][200][HSTR]
            int* __restrict__ arr,            // [200][2][8][ASTR]
            int t0)
{
  const int dir = blockIdx.x >> 7;
  const int lb  = blockIdx.x & 127;    // block within dir
  const int hrow_base = lb * 4;
  const int tid = threadIdx.x;
  const int b = tid & 63;
  const int uw = __builtin_amdgcn_readfirstlane(tid >> 6);  // wave id 0..7
  const int uk0 = uw * 64;                                  // K-offset

  __shared__ float wl[4*4*512];        // [g][rr][k] 32 KB
  __shared__ float part[8*16*64];      // [w][r][b] 32 KB

  const float* whhd = whh + (size_t)dir*2048*512;

  // stage weights ONCE per chunk
  #pragma unroll
  for (int g = 0; g < 4; ++g){
    float4 v = *(const float4*)(whhd + ((size_t)g*512 + hrow_base)*512 + tid*4);
    *(float4*)(&wl[g*2048 + tid*4]) = v;
  }

  // c lives in a register across the chunk (block-local rows)
  const int hr  = tid >> 6;            // 0..3 (only meaningful for tid<256)
  const int hrow = hrow_base + (hr & 3);
  float creg = 0.f;
  if (tid < 256)
    creg = cbuf[((size_t)dir*HID + hrow)*BATCH + b];
  __syncthreads();

  for (int tc = 0; tc < TCH; ++tc){
    const int t = t0 + tc;

    // gate-x prefetch (independent of h) -- hides HBM latency under the spin
    float gx0 = 0.f, gx1 = 0.f, gx2 = 0.f, gx3 = 0.f;
    if (tid < 256){
      const float* gxb = gxc + (size_t)dir*2048*MC + (size_t)tc*BATCH + b;
      gx0 = gxb[(size_t)(   0 + hrow)*MC];
      gx1 = gxb[(size_t)( 512 + hrow)*MC];
      gx2 = gxb[(size_t)(1024 + hrow)*MC];
      gx3 = gxb[(size_t)(1536 + hrow)*MC];
    }

    // per-wave wait: only this wave's 16 producer blocks (group uw).
    int hoff = 0;
    if (t > 0){
      const int* a = arr + (((size_t)(t-1)*2 + dir)*8 + uw)*ASTR;
      int c;
      do {
        c = __hip_atomic_load(a, __ATOMIC_RELAXED, __HIP_MEMORY_SCOPE_AGENT);
        if (c < 16) __builtin_amdgcn_s_sleep(1);
      } while (c < 16);
      // acquire: invalidate any stale/prefetched cache lines before reading
      // h; h base stays data-dependent on this load's result.
      c = __hip_atomic_load(a, __ATOMIC_ACQUIRE, __HIP_MEMORY_SCOPE_AGENT);
      hoff = c >> 5;                       // 16 <= c <= 16  ->  0
      asm volatile("" : "+v"(hoff) : : "memory");
    }

    // this wave's h slice -> registers
    float hv[64];
    if (t > 0){
      const float* hbase = hseq + ((size_t)dir*S_LEN + (t-1))*HSTR + hoff;
      #pragma unroll
      for (int j = 0; j < 64; ++j)
        hv[j] = hbase[(size_t)(uk0 + j)*BATCH + b];
    } else {
      #pragma unroll
      for (int j = 0; j < 64; ++j) hv[j] = 0.f;
    }

    float acc[16];
    #pragma unroll
    for (int r = 0; r < 16; ++r) acc[r] = 0.f;

    #pragma unroll
    for (int r = 0; r < 16; ++r){
      const float* wr = &wl[(r >> 2)*2048 + (r & 3)*512 + uk0]; // wave-uniform
      #pragma unroll
      for (int j4 = 0; j4 < 16; ++j4){
        float4 w = *(const float4*)(wr + j4*4);
        acc[r] += w.x*hv[4*j4] + w.y*hv[4*j4+1] + w.z*hv[4*j4+2] + w.w*hv[4*j4+3];
      }
    }

    #pragma unroll
    for (int r = 0; r < 16; ++r)
      part[(uw*16 + r)*64 + b] = acc[r];
    __syncthreads();

    if (tid < 256){
      float g4[4];
      #pragma unroll
      for (int g = 0; g < 4; ++g){
        const int r = g*4 + hr;
        float s = 0.f;
        #pragma unroll
        for (int ww = 0; ww < 8; ++ww)
          s += part[(ww*16 + r)*64 + b];
        g4[g] = s;
      }
      float gi = g4[0] + gx0;
      float gf = g4[1] + gx1;
      float gg = g4[2] + gx2;
      float go = g4[3] + gx3;
      float si = 1.f/(1.f+expf(-gi));
      float sf = 1.f/(1.f+expf(-gf));
      float so = 1.f/(1.f+expf(-go));
      creg = sf*creg + si*tanhf(gg);
      float h = so*tanhf(creg);
      float* hdst = hseq + ((size_t)dir*S_LEN + t)*HSTR + (size_t)hrow*BATCH + b;
      __hip_atomic_store(hdst, h, __ATOMIC_RELAXED, __HIP_MEMORY_SCOPE_AGENT);
    }
    __syncthreads();   // all h stores of this block retired before signal

    if (tid == 0)
      __hip_atomic_fetch_add(
          arr + (((size_t)t*2 + dir)*8 + (lb >> 4))*ASTR, 1,
          __ATOMIC_RELEASE, __HIP_MEMORY_SCOPE_AGENT);
  }

  // persist c for the next chunk (kernel boundary handles visibility)
  if (tid < 256)
    cbuf[((size_t)dir*HID + hrow)*BATCH + b] = creg;
}

// ---------------------------------------------------------------------------
// Emissions: grid (S_LEN, 2), 256 threads.
__global__ __launch_bounds__(256)
void k_emis(const float* __restrict__ hseq, const int* __restrict__ lengths,
            const float* __restrict__ wpad,   // [2][512][24]
            const float* __restrict__ bout,   // [22]
            float* __restrict__ emisF, float* __restrict__ emisB)
{
  const int t = blockIdx.x;
  const int dir = blockIdx.y;
  const int tid = threadIdx.x;
  const int b = tid & 63;
  const int utg = __builtin_amdgcn_readfirstlane(tid >> 6);  // 0..3

  __shared__ float hl[64*64];          // 16 KB: 64 k-rows x 64 batches

  const float* hsrc = hseq + ((size_t)(dir*S_LEN + t))*HSTR;
  const float* wbase = wpad + (size_t)dir*512*24 + utg*6;

  float acc[6] = {0.f,0.f,0.f,0.f,0.f,0.f};

  for (int c = 0; c < 8; ++c){
    const float4* s4 = (const float4*)(hsrc + (size_t)c*64*64);
    float4* d4 = (float4*)hl;
    #pragma unroll
    for (int q = 0; q < 4; ++q) d4[q*256 + tid] = s4[q*256 + tid];
    __syncthreads();
    const float* wrow = wbase + (size_t)c*64*24;
    #pragma unroll 4
    for (int k = 0; k < 64; ++k){
      float hval = hl[k*64 + b];
      #pragma unroll
      for (int i = 0; i < 6; ++i) acc[i] += hval * wrow[k*24 + i];
    }
    __syncthreads();
  }

  const int len = lengths[b];
  const int pos = dir ? ((t < len) ? (len - 1 - t) : t) : t;
  float* dst = (dir ? emisB : emisF) + ((size_t)b*S_LEN + pos)*NTAG;
  #pragma unroll
  for (int i = 0; i < 6; ++i){
    int tag = utg*6 + i;
    if (tag < NTAG) dst[tag] = acc[i] + (dir ? 0.f : bout[tag]);
  }
}

// ---------------------------------------------------------------------------
// Viterbi: one block = one batch, ONE WAVE. DP state part[j] lives in
// lane j's register; per-step all-to-all broadcast is 22 x v_readlane.
__global__ __launch_bounds__(64)
void k_viterbi(const float* __restrict__ emisF, const float* __restrict__ emisB,
               const int* __restrict__ lengths,
               const float* __restrict__ trans, int* __restrict__ out)
{
  const int b = blockIdx.x;
  const int j = threadIdx.x;           // lane
  __shared__ float esum[S_LEN*NTAG];           // 17.6 KB
  __shared__ unsigned char bp[(S_LEN-1)*NTAG]; // 4.4 KB

  const float* ef = emisF + (size_t)b*S_LEN*NTAG;
  const float* eb = emisB + (size_t)b*S_LEN*NTAG;
  for (int i = j; i < S_LEN*NTAG; i += 64) esum[i] = ef[i] + eb[i];

  const int len = lengths[b];
  float trr[NTAG];
  #pragma unroll
  for (int i = 0; i < NTAG; ++i)
    trr[i] = (j < NTAG) ? trans[i*NTAG + j] : 0.f;
  __syncthreads();

  float p = (j < NTAG) ? (esum[j] + trans[(NTAG-2)*NTAG + j]) : -3.4e38f;

  for (int t = 1; t < S_LEN; ++t){
    float v[NTAG];
    #pragma unroll
    for (int i = 0; i < NTAG; ++i)
      v[i] = rdlane(p, i) + trr[i];
    // 22 -> 11
    float m1[11]; int x1[11];
    #pragma unroll
    for (int i = 0; i < 11; ++i){
      const bool g = v[2*i+1] > v[2*i];
      m1[i] = g ? v[2*i+1] : v[2*i];
      x1[i] = g ? 2*i+1 : 2*i;
    }
    // 11 -> 6
    float m2[6]; int x2[6];
    #pragma unroll
    for (int i = 0; i < 5; ++i){
      const bool g = m1[2*i+1] > m1[2*i];
      m2[i] = g ? m1[2*i+1] : m1[2*i];
      x2[i] = g ? x1[2*i+1] : x1[2*i];
    }
    m2[5] = m1[10]; x2[5] = x1[10];
    // 6 -> 3
    float m3[3]; int x3[3];
    #pragma unroll
    for (int i = 0; i < 3; ++i){
      const bool g = m2[2*i+1] > m2[2*i];
      m3[i] = g ? m2[2*i+1] : m2[2*i];
      x3[i] = g ? x2[2*i+1] : x2[2*i];
    }
    // 3 -> 1
    const bool g01 = m3[1] > m3[0];
    float mm = g01 ? m3[1] : m3[0];
    int   xx = g01 ? x3[1] : x3[0];
    const bool g2 = m3[2] > mm;
    mm = g2 ? m3[2] : mm;
    xx = g2 ? x3[2] : xx;

    const float e = esum[t*NTAG + j];
    if (j < NTAG)
      bp[(t-1)*NTAG + j] = (unsigned char)((t < len) ? xx : j);
    p = (t < len) ? (mm + e) : p;   // t<len is block-uniform
  }
  __syncthreads();

  if (j == 0){
    float best = -3.4e38f; int tag = 0;
    #pragma unroll
    for (int i = 0; i < NTAG; ++i){
      float vv = rdlane(p, i) + trans[i*NTAG + (NTAG-1)];
      if (vv > best){ best = vv; tag = i; }
    }
    out[b*S_LEN + S_LEN-1] = (S_LEN-1 < len) ? tag : 0;
    for (int t = S_LEN-2; t >= 0; --t){
      tag = bp[t*NTAG + tag];
      out[b*S_LEN + t] = (t < len) ? tag : 0;
    }
  }
}

// ---------------------------------------------------------------------------
extern "C" void kernel_launch(void* const* d_in, const int* in_sizes, int n_in,
                              void* d_out, int out_size, void* d_ws, size_t ws_size,
                              hipStream_t stream)
{
  (void)in_sizes; (void)n_in; (void)out_size; (void)ws_size;
  const int* char_inputs  = (const int*)d_in[0];
  const int* lengths      = (const int*)d_in[1];
  const int* gaz_ids      = (const int*)d_in[3];
  const int* gaz_mask     = (const int*)d_in[4];
  const int* rev_gaz_ids  = (const int*)d_in[5];
  const int* rev_gaz_mask = (const int*)d_in[6];
  const void* char_table  = d_in[7];
  const void* gaz_table   = d_in[8];
  const void* w_ih_f = d_in[9];
  const void* w_hh_f = d_in[10];
  const void* b_f    = d_in[11];
  const void* w_ih_b = d_in[12];
  const void* w_hh_b = d_in[13];
  const void* b_b    = d_in[14];
  const void* W_out  = d_in[15];
  const void* b_out  = d_in[16];
  const void* trans  = d_in[17];

  char* ws = (char*)d_ws;
  size_t off = 0;
  auto alloc = [&](size_t bytes)->char*{
    char* p = ws + off; off = (off + bytes + 255) & ~(size_t)255; return p;
  };
  int*   flag   = (int*)  alloc(256);
  float* whh32  = (float*)alloc(2ull*2048*512*4);   //  8.4 MB
  float* wih32  = (float*)alloc(2ull*2048*256*4);   //  4.2 MB
  float* bias32 = (float*)alloc(2ull*2048*4);
  float* wpad   = (float*)alloc(2ull*512*24*4);
  float* bout32 = (float*)alloc(22ull*4);
  float* trans32= (float*)alloc(484ull*4);
  float* fwd_in = (float*)alloc(12800ull*256*4);    // 13.1 MB
  float* bwd_in = (float*)alloc(12800ull*256*4);    // 13.1 MB
  float* gxc    = (float*)alloc(2ull*2048*MC*4);    // 41.9 MB
  float* cbuf   = (float*)alloc(2ull*512*64*4);
  int*   arrival= (int*)  alloc(200ull*2*8*ASTR*4); //  3.3 MB padded step flags
  float* hseq   = (float*)alloc(2ull*200*HSTR*4);   // 52.8 MB (padded)
  float* emisF  = (float*)alloc(12800ull*22*4);
  float* emisB  = (float*)alloc(12800ull*22*4);

  k_detect<<<1,256,0,stream>>>((const u32*)char_table, flag);
  k_cvt_f<<<4096,256,0,stream>>>(w_hh_f, whh32,           1048576, flag);
  k_cvt_f<<<4096,256,0,stream>>>(w_hh_b, whh32 + 1048576, 1048576, flag);
  k_cvt_f<<<2048,256,0,stream>>>(w_ih_f, wih32,            524288, flag);
  k_cvt_f<<<2048,256,0,stream>>>(w_ih_b, wih32 + 524288,   524288, flag);
  k_cvt_f<<<8,256,0,stream>>>(b_f, bias32,        2048, flag);
  k_cvt_f<<<8,256,0,stream>>>(b_b, bias32 + 2048, 2048, flag);
  k_cvt_wt<<<96,256,0,stream>>>(W_out, wpad, flag);
  k_cvt_f<<<1,256,0,stream>>>(b_out, bout32, 22, flag);
  k_cvt_f<<<2,256,0,stream>>>(trans, trans32, 484, flag);

  k_build<<<12800,128,0,stream>>>(char_inputs, lengths, gaz_ids, gaz_mask,
                                  rev_gaz_ids, rev_gaz_mask, char_table, gaz_table,
                                  flag, fwd_in, bwd_in);

  k_zero<<<256,256,0,stream>>>(cbuf, 2*512*64);
  k_zero<<<800,256,0,stream>>>((float*)arrival, 200*2*8*ASTR);

  for (int t0 = 0; t0 < S_LEN; t0 += TCH){
    k_gemm_ih<<<dim3(16,MC/128,2),256,0,stream>>>(fwd_in, bwd_in, wih32, bias32,
                                                  gxc, t0);
    hipLaunchKernelGGL(k_lstm, dim3(256), dim3(512), 0, stream,
                       whh32, gxc, cbuf, hseq, arrival, t0);
  }

  k_emis<<<dim3(S_LEN,2),256,0,stream>>>(hseq, lengths, wpad, bout32, emisF, emisB);
  k_viterbi<<<64,64,0,stream>>>(emisF, emisB, lengths, trans32, (int*)d_out);
}

// Round 16
// 2522.360 us; speedup vs baseline: 2.4290x; 2.4290x over previous
//
#include <hip/hip_runtime.h>
#include <math.h>

#define S_LEN 200
#define BATCH 64
#define HID   512
#define NTAG  22
#define TCH   40              // time-chunk for gates_x staging (MC=2560 = 20 x 128)
#define MC    (TCH*BATCH)     // 2560 rows per chunk GEMM
#define HSTR  (HID*BATCH + 256)   // padded h-slice stride
#define ASTR  64              // ints per arrival stripe (256 B -> own cacheline)

typedef unsigned short u16;
typedef unsigned int   u32;

__device__ __forceinline__ float bf2f(u16 u){
  union { u32 ui; float f; } v; v.ui = ((u32)u) << 16; return v.f;
}

__device__ __forceinline__ float rdlane(float x, int lane){
  return __int_as_float(__builtin_amdgcn_readlane(__float_as_int(x), lane));
}

// ---------------------------------------------------------------------------
__global__ void k_detect(const u32* __restrict__ w, int* __restrict__ flag){
  __shared__ int cnt;
  if (threadIdx.x == 0) cnt = 0;
  __syncthreads();
  int hits = 0;
  for (int i = threadIdx.x; i < 16384; i += 256){
    u32 e = (w[i] & 0x7F80u);
    if (e >= 0x3800u && e <= 0x4080u) hits++;
  }
  atomicAdd(&cnt, hits);
  __syncthreads();
  if (threadIdx.x == 0) *flag = (cnt > 8192) ? 1 : 0;
}

__global__ void k_cvt_f(const void* __restrict__ src, float* __restrict__ dst,
                        int n, const int* __restrict__ flag){
  int i = blockIdx.x*blockDim.x + threadIdx.x;
  if (i >= n) return;
  if (*flag) dst[i] = bf2f(((const u16*)src)[i]);
  else       dst[i] = ((const float*)src)[i];
}

// W_out [1024][22] -> wpad [2][512][24]  (tag-padded, k-major per half)
__global__ void k_cvt_wt(const void* __restrict__ src, float* __restrict__ dst,
                         const int* __restrict__ flag){
  int i = blockIdx.x*blockDim.x + threadIdx.x;   // over 1024*24
  if (i >= 1024*24) return;
  int k = i / 24, tag = i % 24;
  float v = 0.f;
  if (tag < NTAG){
    v = (*flag) ? bf2f(((const u16*)src)[k*NTAG + tag])
                : ((const float*)src)[k*NTAG + tag];
  }
  int half = k >> 9, kk = k & 511;
  dst[((size_t)half*512 + kk)*24 + tag] = v;
}

__global__ void k_zero(float* __restrict__ p, int n){
  int i = blockIdx.x*blockDim.x + threadIdx.x;
  if (i < n) p[i] = 0.f;
}

// ---------------------------------------------------------------------------
// Build fwd_in/bwd_in [S][B][256] fp32.
__global__ __launch_bounds__(128)
void k_build(const int* __restrict__ ci, const int* __restrict__ lengths,
             const int* __restrict__ gid, const int* __restrict__ gm,
             const int* __restrict__ rgid, const int* __restrict__ rgm,
             const void* __restrict__ ctab, const void* __restrict__ gtab,
             const int* __restrict__ flag,
             float* __restrict__ fin, float* __restrict__ bin)
{
  int bs = blockIdx.x;              // b*S_LEN + s
  int b = bs / S_LEN, s = bs % S_LEN;
  int d = threadIdx.x;              // 0..127
  int isbf = *flag;
  int len = lengths[b];
  int sb = (s < len) ? (len - 1 - s) : s;
  size_t orow = ((size_t)s*BATCH + b)*256;

  {
    int cid = ci[bs];
    float cv = isbf ? bf2f(((const u16*)ctab)[(size_t)cid*128 + d])
                    : ((const float*)ctab)[(size_t)cid*128 + d];
    fin[orow + d] = cv;
    const int* gg = gid + (size_t)bs*8;
    const int* mm = gm  + (size_t)bs*8;
    float sum = 0.f, cntf = 0.f;
    for (int g = 0; g < 8; ++g){
      float m = (float)mm[g];
      int gw = gg[g];
      float gv = isbf ? bf2f(((const u16*)gtab)[(size_t)gw*128 + d])
                      : ((const float*)gtab)[(size_t)gw*128 + d];
      sum += m * gv; cntf += m;
    }
    fin[orow + 128 + d] = sum / fmaxf(cntf, 1.f);
  }
  {
    int bsr = b*S_LEN + sb;
    int cid = ci[bsr];
    float cv = isbf ? bf2f(((const u16*)ctab)[(size_t)cid*128 + d])
                    : ((const float*)ctab)[(size_t)cid*128 + d];
    bin[orow + d] = cv;
    const int* gg = rgid + (size_t)bsr*8;
    const int* mm = rgm  + (size_t)bsr*8;
    float sum = 0.f, cntf = 0.f;
    for (int g = 0; g < 8; ++g){
      float m = (float)mm[g];
      int gw = gg[g];
      float gv = isbf ? bf2f(((const u16*)gtab)[(size_t)gw*128 + d])
                      : ((const float*)gtab)[(size_t)gw*128 + d];
      sum += m * gv; cntf += m;
    }
    bin[orow + 128 + d] = sum / fmaxf(cntf, 1.f);
  }
}

// ---------------------------------------------------------------------------
// Chunked gates_x GEMM: C[dir][n][m] = A.W^T + bias (transposed store).
// 128x128 block tile, 256 threads, 8x8 microtile.
__global__ __launch_bounds__(256)
void k_gemm_ih(const float* __restrict__ Af, const float* __restrict__ Ab,
               const float* __restrict__ wih,   // [2][2048][256]
               const float* __restrict__ bias,  // [2][2048]
               float* __restrict__ gxc,         // [2][2048][MC]
               int t0)
{
  const int dir = blockIdx.z;
  const float* A = (dir ? Ab : Af) + (size_t)t0*BATCH*256;   // [MC][256]
  const float* W = wih + (size_t)dir*2048*256;
  const float* bi = bias + (size_t)dir*2048;
  float* C = gxc + (size_t)dir*2048*MC;
  const int m0 = blockIdx.y * 128;
  const int n0 = blockIdx.x * 128;
  const int tid = threadIdx.x;

  __shared__ float As[32][132];   // k-major, padded
  __shared__ float Ws[32][132];

  const int lrow = tid >> 3;        // 0..31
  const int lk   = (tid & 7) * 4;   // 0,4,..,28

  const int tx = tid & 15;          // n-frag
  const int ty = tid >> 4;          // m-frag

  float acc[8][8] = {};

  for (int k0 = 0; k0 < 256; k0 += 32){
    #pragma unroll
    for (int q = 0; q < 4; ++q){
      const int row = lrow + q*32;
      float4 a = *(const float4*)(A + (size_t)(m0+row)*256 + k0 + lk);
      float4 w = *(const float4*)(W + (size_t)(n0+row)*256 + k0 + lk);
      As[lk+0][row]=a.x; As[lk+1][row]=a.y; As[lk+2][row]=a.z; As[lk+3][row]=a.w;
      Ws[lk+0][row]=w.x; Ws[lk+1][row]=w.y; Ws[lk+2][row]=w.z; Ws[lk+3][row]=w.w;
    }
    __syncthreads();
    #pragma unroll 8
    for (int kk = 0; kk < 32; ++kk){
      float4 a0 = *(const float4*)(&As[kk][ty*8]);
      float4 a1 = *(const float4*)(&As[kk][ty*8+4]);
      float4 w0 = *(const float4*)(&Ws[kk][tx*8]);
      float4 w1 = *(const float4*)(&Ws[kk][tx*8+4]);
      float am[8] = {a0.x,a0.y,a0.z,a0.w,a1.x,a1.y,a1.z,a1.w};
      float wn[8] = {w0.x,w0.y,w0.z,w0.w,w1.x,w1.y,w1.z,w1.w};
      #pragma unroll
      for (int i = 0; i < 8; ++i)
        #pragma unroll
        for (int jj = 0; jj < 8; ++jj)
          acc[i][jj] += am[i]*wn[jj];
    }
    __syncthreads();
  }

  #pragma unroll
  for (int jj = 0; jj < 8; ++jj){
    const int n = n0 + tx*8 + jj;
    const float bj = bi[n];
    #pragma unroll
    for (int i = 0; i < 8; i += 4){
      float4 o = make_float4(acc[i][jj]+bj, acc[i+1][jj]+bj,
                             acc[i+2][jj]+bj, acc[i+3][jj]+bj);
      *(float4*)(C + (size_t)n*MC + m0 + ty*8 + i) = o;
    }
  }
}

// ---------------------------------------------------------------------------
// Persistent LSTM, r8 sync structure (PROVEN: global 128-block fan-in +
// relaxed atomics + __syncthreads release; r13 confirmed the race theory but
// showed release/acquire cache maintenance costs ~18us/step -> rejected).
// r14 change vs r8: the poll is PARALLEL -- lanes 0..7 each spin on their own
// stripe concurrently (divergent loop) instead of tid0's 8 serial L3
// round-trips. Block release still via __syncthreads (r8's compiler+HW
// barrier). Producer side, math, accumulation order byte-identical to r8.
__global__ __launch_bounds__(512, 1)
void k_lstm(const float* __restrict__ whh,    // [2][2048][512]
            const float* __restrict__ gxc,    // [2][2048][MC]
            float* __restrict__ cbuf,         // [2][512][64]
            float* __restrict__ hseq,         // [2][200][HSTR]
            int* __restrict__ arr,            // [200][2][8][ASTR]
            int t0)
{
  const int dir = blockIdx.x >> 7;
  const int lb  = blockIdx.x & 127;    // block within dir
  const int hrow_base = lb * 4;
  const int tid = threadIdx.x;
  const int b = tid & 63;
  const int uw = __builtin_amdgcn_readfirstlane(tid >> 6);  // wave id 0..7
  const int uk0 = uw * 64;                                  // K-offset

  __shared__ float wl[4*4*512];        // [g][rr][k] 32 KB
  __shared__ float part[8*16*64];      // [w][r][b] 32 KB

  const float* whhd = whh + (size_t)dir*2048*512;

  // stage weights ONCE per chunk
  #pragma unroll
  for (int g = 0; g < 4; ++g){
    float4 v = *(const float4*)(whhd + ((size_t)g*512 + hrow_base)*512 + tid*4);
    *(float4*)(&wl[g*2048 + tid*4]) = v;
  }

  // c lives in a register across the chunk (block-local rows)
  const int hr  = tid >> 6;            // 0..3 (only meaningful for tid<256)
  const int hrow = hrow_base + (hr & 3);
  float creg = 0.f;
  if (tid < 256)
    creg = cbuf[((size_t)dir*HID + hrow)*BATCH + b];
  __syncthreads();

  for (int tc = 0; tc < TCH; ++tc){
    const int t = t0 + tc;

    // gate-x prefetch (independent of h) -- hides HBM latency under the spin
    float gx0 = 0.f, gx1 = 0.f, gx2 = 0.f, gx3 = 0.f;
    if (tid < 256){
      const float* gxb = gxc + (size_t)dir*2048*MC + (size_t)tc*BATCH + b;
      gx0 = gxb[(size_t)(   0 + hrow)*MC];
      gx1 = gxb[(size_t)( 512 + hrow)*MC];
      gx2 = gxb[(size_t)(1024 + hrow)*MC];
      gx3 = gxb[(size_t)(1536 + hrow)*MC];
    }

    // wait until all 128 blocks of this dir published h_{t-1}.
    // Parallel poll: lane q spins on stripe q (each stripe saturates at 16).
    if (t > 0){
      if (tid < 8){
        const int* a = arr + (((size_t)(t-1)*2 + dir)*8 + tid)*ASTR;
        while (__hip_atomic_load(a, __ATOMIC_RELAXED,
                                 __HIP_MEMORY_SCOPE_AGENT) < 16)
          __builtin_amdgcn_s_sleep(1);
      }
      __syncthreads();
    }

    // this wave's h slice -> registers
    float hv[64];
    if (t > 0){
      const float* hbase = hseq + ((size_t)dir*S_LEN + (t-1))*HSTR;
      #pragma unroll
      for (int j = 0; j < 64; ++j)
        hv[j] = hbase[(size_t)(uk0 + j)*BATCH + b];
    } else {
      #pragma unroll
      for (int j = 0; j < 64; ++j) hv[j] = 0.f;
    }

    float acc[16];
    #pragma unroll
    for (int r = 0; r < 16; ++r) acc[r] = 0.f;

    #pragma unroll
    for (int r = 0; r < 16; ++r){
      const float* wr = &wl[(r >> 2)*2048 + (r & 3)*512 + uk0]; // wave-uniform
      #pragma unroll
      for (int j4 = 0; j4 < 16; ++j4){
        float4 w = *(const float4*)(wr + j4*4);
        acc[r] += w.x*hv[4*j4] + w.y*hv[4*j4+1] + w.z*hv[4*j4+2] + w.w*hv[4*j4+3];
      }
    }

    #pragma unroll
    for (int r = 0; r < 16; ++r)
      part[(uw*16 + r)*64 + b] = acc[r];
    __syncthreads();

    if (tid < 256){
      float g4[4];
      #pragma unroll
      for (int g = 0; g < 4; ++g){
        const int r = g*4 + hr;
        float s = 0.f;
        #pragma unroll
        for (int ww = 0; ww < 8; ++ww)
          s += part[(ww*16 + r)*64 + b];
        g4[g] = s;
      }
      float gi = g4[0] + gx0;
      float gf = g4[1] + gx1;
      float gg = g4[2] + gx2;
      float go = g4[3] + gx3;
      float si = 1.f/(1.f+expf(-gi));
      float sf = 1.f/(1.f+expf(-gf));
      float so = 1.f/(1.f+expf(-go));
      creg = sf*creg + si*tanhf(gg);
      float h = so*tanhf(creg);
      float* hdst = hseq + ((size_t)dir*S_LEN + t)*HSTR + (size_t)hrow*BATCH + b;
      __hip_atomic_store(hdst, h, __ATOMIC_RELAXED, __HIP_MEMORY_SCOPE_AGENT);
    }
    __syncthreads();   // implicit s_waitcnt vmcnt(0): sc1 stores are at L3

    if (tid == 0)
      __hip_atomic_fetch_add(
          arr + (((size_t)t*2 + dir)*8 + (lb & 7))*ASTR, 1,
          __ATOMIC_RELAXED, __HIP_MEMORY_SCOPE_AGENT);
  }

  // persist c for the next chunk (kernel boundary handles visibility)
  if (tid < 256)
    cbuf[((size_t)dir*HID + hrow)*BATCH + b] = creg;
}

// ---------------------------------------------------------------------------
// Emissions: grid (S_LEN, 2), 256 threads.
__global__ __launch_bounds__(256)
void k_emis(const float* __restrict__ hseq, const int* __restrict__ lengths,
            const float* __restrict__ wpad,   // [2][512][24]
            const float* __restrict__ bout,   // [22]
            float* __restrict__ emisF, float* __restrict__ emisB)
{
  const int t = blockIdx.x;
  const int dir = blockIdx.y;
  const int tid = threadIdx.x;
  const int b = tid & 63;
  const int utg = __builtin_amdgcn_readfirstlane(tid >> 6);  // 0..3

  __shared__ float hl[64*64];          // 16 KB: 64 k-rows x 64 batches

  const float* hsrc = hseq + ((size_t)(dir*S_LEN + t))*HSTR;
  const float* wbase = wpad + (size_t)dir*512*24 + utg*6;

  float acc[6] = {0.f,0.f,0.f,0.f,0.f,0.f};

  for (int c = 0; c < 8; ++c){
    const float4* s4 = (const float4*)(hsrc + (size_t)c*64*64);
    float4* d4 = (float4*)hl;
    #pragma unroll
    for (int q = 0; q < 4; ++q) d4[q*256 + tid] = s4[q*256 + tid];
    __syncthreads();
    const float* wrow = wbase + (size_t)c*64*24;
    #pragma unroll 4
    for (int k = 0; k < 64; ++k){
      float hval = hl[k*64 + b];
      #pragma unroll
      for (int i = 0; i < 6; ++i) acc[i] += hval * wrow[k*24 + i];
    }
    __syncthreads();
  }

  const int len = lengths[b];
  const int pos = dir ? ((t < len) ? (len - 1 - t) : t) : t;
  float* dst = (dir ? emisB : emisF) + ((size_t)b*S_LEN + pos)*NTAG;
  #pragma unroll
  for (int i = 0; i < 6; ++i){
    int tag = utg*6 + i;
    if (tag < NTAG) dst[tag] = acc[i] + (dir ? 0.f : bout[tag]);
  }
}

// ---------------------------------------------------------------------------
// Viterbi v4: one block = one batch, ONE WAVE. DP state part[j] in lane j's
// register (22 x v_readlane broadcast). r14 change: the per-step argmax no
// longer carries indices through a cmp/cndmask tree (long dependent chain).
// Instead: (1) value-only max via fmaxf triples (fuses to v_max3_f32,
// depth ~4); (2) argmax = parallel equality scan v[i]==mm -> bitmask ->
// ctz. Float equality (not bitwise: +-0) picks the FIRST index attaining
// the max == reference strict-> first-occurrence semantics, and max returns
// one of its operands so the mask is non-empty. Chain ~1600 -> ~400 cy/step.
__global__ __launch_bounds__(64)
void k_viterbi(const float* __restrict__ emisF, const float* __restrict__ emisB,
               const int* __restrict__ lengths,
               const float* __restrict__ trans, int* __restrict__ out)
{
  const int b = blockIdx.x;
  const int j = threadIdx.x;           // lane
  __shared__ float esum[S_LEN*NTAG];           // 17.6 KB
  __shared__ unsigned char bp[(S_LEN-1)*NTAG]; // 4.4 KB

  const float* ef = emisF + (size_t)b*S_LEN*NTAG;
  const float* eb = emisB + (size_t)b*S_LEN*NTAG;
  for (int i = j; i < S_LEN*NTAG; i += 64) esum[i] = ef[i] + eb[i];

  const int len = lengths[b];
  float trr[NTAG];
  #pragma unroll
  for (int i = 0; i < NTAG; ++i)
    trr[i] = (j < NTAG) ? trans[i*NTAG + j] : 0.f;
  __syncthreads();

  float p = (j < NTAG) ? (esum[j] + trans[(NTAG-2)*NTAG + j]) : -3.4e38f;

  for (int t = 1; t < S_LEN; ++t){
    float v[NTAG];
    #pragma unroll
    for (int i = 0; i < NTAG; ++i)
      v[i] = rdlane(p, i) + trr[i];

    // value max: 22 -> 8 -> 3 -> 1 (fmaxf triples fuse to v_max3_f32)
    float a0 = fmaxf(fmaxf(v[0],v[1]),v[2]);
    float a1 = fmaxf(fmaxf(v[3],v[4]),v[5]);
    float a2 = fmaxf(fmaxf(v[6],v[7]),v[8]);
    float a3 = fmaxf(fmaxf(v[9],v[10]),v[11]);
    float a4 = fmaxf(fmaxf(v[12],v[13]),v[14]);
    float a5 = fmaxf(fmaxf(v[15],v[16]),v[17]);
    float a6 = fmaxf(fmaxf(v[18],v[19]),v[20]);
    float b0 = fmaxf(fmaxf(a0,a1),a2);
    float b1 = fmaxf(fmaxf(a3,a4),a5);
    float b2 = fmaxf(a6, v[21]);
    const float mm = fmaxf(fmaxf(b0,b1),b2);

    // argmax: first i with v[i] == mm (float equality; mask non-empty)
    u32 mk = 0;
    #pragma unroll
    for (int i = 0; i < NTAG; ++i)
      mk |= (v[i] == mm) ? (1u << i) : 0u;
    const int xx = (int)__builtin_ctz(mk | 0x80000000u);

    const float e = esum[t*NTAG + j];
    if (j < NTAG)
      bp[(t-1)*NTAG + j] = (unsigned char)((t < len) ? xx : j);
    p = (t < len) ? (mm + e) : p;   // t<len is block-uniform
  }
  __syncthreads();

  if (j == 0){
    float best = -3.4e38f; int tag = 0;
    #pragma unroll
    for (int i = 0; i < NTAG; ++i){
      float vv = rdlane(p, i) + trans[i*NTAG + (NTAG-1)];
      if (vv > best){ best = vv; tag = i; }
    }
    out[b*S_LEN + S_LEN-1] = (S_LEN-1 < len) ? tag : 0;
    for (int t = S_LEN-2; t >= 0; --t){
      tag = bp[t*NTAG + tag];
      out[b*S_LEN + t] = (t < len) ? tag : 0;
    }
  }
}

// ---------------------------------------------------------------------------
extern "C" void kernel_launch(void* const* d_in, const int* in_sizes, int n_in,
                              void* d_out, int out_size, void* d_ws, size_t ws_size,
                              hipStream_t stream)
{
  (void)in_sizes; (void)n_in; (void)out_size; (void)ws_size;
  const int* char_inputs  = (const int*)d_in[0];
  const int* lengths      = (const int*)d_in[1];
  const int* gaz_ids      = (const int*)d_in[3];
  const int* gaz_mask     = (const int*)d_in[4];
  const int* rev_gaz_ids  = (const int*)d_in[5];
  const int* rev_gaz_mask = (const int*)d_in[6];
  const void* char_table  = d_in[7];
  const void* gaz_table   = d_in[8];
  const void* w_ih_f = d_in[9];
  const void* w_hh_f = d_in[10];
  const void* b_f    = d_in[11];
  const void* w_ih_b = d_in[12];
  const void* w_hh_b = d_in[13];
  const void* b_b    = d_in[14];
  const void* W_out  = d_in[15];
  const void* b_out  = d_in[16];
  const void* trans  = d_in[17];

  char* ws = (char*)d_ws;
  size_t off = 0;
  auto alloc = [&](size_t bytes)->char*{
    char* p = ws + off; off = (off + bytes + 255) & ~(size_t)255; return p;
  };
  int*   flag   = (int*)  alloc(256);
  float* whh32  = (float*)alloc(2ull*2048*512*4);   //  8.4 MB
  float* wih32  = (float*)alloc(2ull*2048*256*4);   //  4.2 MB
  float* bias32 = (float*)alloc(2ull*2048*4);
  float* wpad   = (float*)alloc(2ull*512*24*4);
  float* bout32 = (float*)alloc(22ull*4);
  float* trans32= (float*)alloc(484ull*4);
  float* fwd_in = (float*)alloc(12800ull*256*4);    // 13.1 MB
  float* bwd_in = (float*)alloc(12800ull*256*4);    // 13.1 MB
  float* gxc    = (float*)alloc(2ull*2048*MC*4);    // 41.9 MB
  float* cbuf   = (float*)alloc(2ull*512*64*4);
  int*   arrival= (int*)  alloc(200ull*2*8*ASTR*4); //  3.3 MB padded step flags
  float* hseq   = (float*)alloc(2ull*200*HSTR*4);   // 52.8 MB (padded)
  float* emisF  = (float*)alloc(12800ull*22*4);
  float* emisB  = (float*)alloc(12800ull*22*4);

  k_detect<<<1,256,0,stream>>>((const u32*)char_table, flag);
  k_cvt_f<<<4096,256,0,stream>>>(w_hh_f, whh32,           1048576, flag);
  k_cvt_f<<<4096,256,0,stream>>>(w_hh_b, whh32 + 1048576, 1048576, flag);
  k_cvt_f<<<2048,256,0,stream>>>(w_ih_f, wih32,            524288, flag);
  k_cvt_f<<<2048,256,0,stream>>>(w_ih_b, wih32 + 524288,   524288, flag);
  k_cvt_f<<<8,256,0,stream>>>(b_f, bias32,        2048, flag);
  k_cvt_f<<<8,256,0,stream>>>(b_b, bias32 + 2048, 2048, flag);
  k_cvt_wt<<<96,256,0,stream>>>(W_out, wpad, flag);
  k_cvt_f<<<1,256,0,stream>>>(b_out, bout32, 22, flag);
  k_cvt_f<<<2,256,0,stream>>>(trans, trans32, 484, flag);

  k_build<<<12800,128,0,stream>>>(char_inputs, lengths, gaz_ids, gaz_mask,
                                  rev_gaz_ids, rev_gaz_mask, char_table, gaz_table,
                                  flag, fwd_in, bwd_in);

  k_zero<<<256,256,0,stream>>>(cbuf, 2*512*64);
  k_zero<<<800,256,0,stream>>>((float*)arrival, 200*2*8*ASTR);

  for (int t0 = 0; t0 < S_LEN; t0 += TCH){
    k_gemm_ih<<<dim3(16,MC/128,2),256,0,stream>>>(fwd_in, bwd_in, wih32, bias32,
                                                  gxc, t0);
    hipLaunchKernelGGL(k_lstm, dim3(256), dim3(512), 0, stream,
                       whh32, gxc, cbuf, hseq, arrival, t0);
  }

  k_emis<<<dim3(S_LEN,2),256,0,stream>>>(hseq, lengths, wpad, bout32, emisF, emisB);
  k_viterbi<<<64,64,0,stream>>>(emisF, emisB, lengths, trans32, (int*)d_out);
}